// Round 1
// baseline (797.880 us; speedup 1.0000x reference)
//
#include <hip/hip_runtime.h>
#include <math.h>

#define NNODES 50000
#define NFEAT  128
#define NEDGE  800000
#define ETOT   (NEDGE + NNODES)   // 850000 edges incl. self-loops
#define H1     4
#define O1     256                // heads1 * hid1
#define C2     128
#define C3     10
#define NGRAPH 512

static_assert(NNODES % 4 == 0, "waves per block mapping");

// ---------------- CSR build ----------------

__global__ void k_count(const int* __restrict__ dst_e, int* __restrict__ deg) {
  int e = blockIdx.x * 256 + threadIdx.x;
  if (e >= ETOT) return;
  int d = (e < NEDGE) ? dst_e[e] : (e - NEDGE);
  atomicAdd(&deg[d], 1);
}

__global__ __launch_bounds__(1024) void k_scan(const int* __restrict__ deg,
                                               int* __restrict__ rowptr,
                                               int* __restrict__ cursor) {
  __shared__ int tmp[1024];
  __shared__ int carry_s;
  const int tid = threadIdx.x;
  if (tid == 0) { carry_s = 0; rowptr[0] = 0; }
  __syncthreads();
  for (int base = 0; base < NNODES; base += 1024) {
    int idx = base + tid;
    int v = (idx < NNODES) ? deg[idx] : 0;
    tmp[tid] = v;
    __syncthreads();
    for (int off = 1; off < 1024; off <<= 1) {
      int t = (tid >= off) ? tmp[tid - off] : 0;
      __syncthreads();
      tmp[tid] += t;
      __syncthreads();
    }
    int incl = tmp[tid];
    int cbase = carry_s;
    if (idx < NNODES) {
      rowptr[idx + 1] = cbase + incl;
      cursor[idx] = cbase + incl - v;   // exclusive prefix = scatter base
    }
    __syncthreads();
    if (tid == 1023) carry_s = cbase + tmp[1023];
    __syncthreads();
  }
}

__global__ void k_scatter(const int* __restrict__ dst_e, int* __restrict__ cursor,
                          int* __restrict__ eid) {
  int e = blockIdx.x * 256 + threadIdx.x;
  if (e >= ETOT) return;
  int d = (e < NEDGE) ? dst_e[e] : (e - NEDGE);
  int pos = atomicAdd(&cursor[d], 1);
  eid[pos] = e;
}

// ---------------- dense GEMM: H = X @ W ----------------
// 256 threads; block computes TM rows x OUTC cols. OUTP = padded OUTC dividing 256.

template<int K, int OUTC, int OUTP, int TM>
__global__ __launch_bounds__(256) void k_gemm(const float* __restrict__ X,
                                              const float* __restrict__ W,
                                              float* __restrict__ Hout) {
  constexpr int GROUPS = 256 / OUTP;
  constexpr int RPT = TM / GROUPS;
  __shared__ float xs[TM][K];
  const int tid = threadIdx.x;
  const int row0 = blockIdx.x * TM;
  for (int i = tid * 4; i < TM * K; i += 1024) {
    int r = i / K, c = i % K;
    int gr = row0 + r;
    float4 v;
    if (gr < NNODES) v = *(const float4*)(X + (size_t)gr * K + c);
    else v = make_float4(0.f, 0.f, 0.f, 0.f);
    *(float4*)(&xs[r][c]) = v;
  }
  __syncthreads();
  const int col = tid % OUTP;
  const int g = tid / OUTP;
  if (col < OUTC) {
    float acc[RPT];
#pragma unroll
    for (int r = 0; r < RPT; ++r) acc[r] = 0.f;
    for (int k = 0; k < K; ++k) {
      float wv = W[(size_t)k * OUTC + col];
#pragma unroll
      for (int r = 0; r < RPT; ++r)
        acc[r] += xs[g * RPT + r][k] * wv;
    }
#pragma unroll
    for (int r = 0; r < RPT; ++r) {
      int gr = row0 + g * RPT + r;
      if (gr < NNODES) Hout[(size_t)gr * OUTC + col] = acc[r];
    }
  }
}

// ---------------- attention logits: al_s/al_d per node ----------------

template<int HEADS, int C>
__global__ __launch_bounds__(256) void k_att(const float* __restrict__ Hm,
                                             const float* __restrict__ a_src,
                                             const float* __restrict__ a_dst,
                                             float* __restrict__ als,
                                             float* __restrict__ ald) {
  constexpr int TOT = HEADS * C;
  constexpr int V = (TOT + 63) / 64;
  int wave = blockIdx.x * 4 + (threadIdx.x >> 6);
  int lane = threadIdx.x & 63;
  if (wave >= NNODES) return;
  float s = 0.f, d = 0.f;
  int ch0 = lane * V;
#pragma unroll
  for (int v = 0; v < V; ++v) {
    int ch = ch0 + v;
    if ((TOT % 64 == 0) || ch < TOT) {
      float hv = Hm[(size_t)wave * TOT + ch];
      s += hv * a_src[ch];
      d += hv * a_dst[ch];
    }
  }
  constexpr int RW = (HEADS == 1) ? 64 : 16;
#pragma unroll
  for (int m = 1; m < RW; m <<= 1) { s += __shfl_xor(s, m); d += __shfl_xor(d, m); }
  if ((lane & (RW - 1)) == 0) {
    int h = lane / RW;
    if (h < HEADS) {
      als[(size_t)wave * HEADS + h] = s;
      ald[(size_t)wave * HEADS + h] = d;
    }
  }
}

// ---------------- fused softmax + aggregation, one wave per dst node ----------------

template<int HEADS, int C, bool ACT>
__global__ __launch_bounds__(256) void k_agg(const int* __restrict__ rowptr,
                                             const int* __restrict__ eid,
                                             const int* __restrict__ src_e,
                                             const float* __restrict__ Hm,
                                             const float* __restrict__ als,
                                             const float* __restrict__ ald,
                                             const float* __restrict__ bias,
                                             float* __restrict__ alpha,
                                             float* __restrict__ outbuf) {
  constexpr int TOT = HEADS * C;
  constexpr int V = (TOT + 63) / 64;
  const int wave = blockIdx.x * 4 + (threadIdx.x >> 6);
  const int lane = threadIdx.x & 63;
  const int n = wave;
  const int r0 = rowptr[n], r1 = rowptr[n + 1];

  // phase 1: exp(leaky_relu(al_s[src]+al_d[n])) per edge, accumulate denominator
  float aldv[HEADS], den[HEADS];
#pragma unroll
  for (int h = 0; h < HEADS; ++h) { aldv[h] = ald[(size_t)n * HEADS + h]; den[h] = 0.f; }
  for (int i = r0 + lane; i < r1; i += 64) {
    int e = eid[i];
    int s = (e < NEDGE) ? src_e[e] : (e - NEDGE);
    float exv[HEADS];
#pragma unroll
    for (int h = 0; h < HEADS; ++h) {
      float ev = als[(size_t)s * HEADS + h] + aldv[h];
      ev = (ev > 0.f) ? ev : 0.2f * ev;
      float ex = __expf(ev);
      den[h] += ex;
      exv[h] = ex;
    }
    if constexpr (HEADS == 4) {
      *(float4*)(alpha + (size_t)i * 4) = make_float4(exv[0], exv[1], exv[2], exv[3]);
    } else {
      alpha[i] = exv[0];
    }
  }
#pragma unroll
  for (int h = 0; h < HEADS; ++h) {
#pragma unroll
    for (int m = 1; m < 64; m <<= 1) den[h] += __shfl_xor(den[h], m);
  }
  float rden[HEADS];
#pragma unroll
  for (int h = 0; h < HEADS; ++h) rden[h] = 1.f / (den[h] + 1e-16f);

  __syncthreads();   // make per-lane alpha stores visible wave/block-wide

  // phase 2: out[n] = sum_e alpha_e * h[src_e], channels across lanes
  const int ch0 = lane * V;
  constexpr bool FULL = (TOT % 64 == 0);
  const bool active = FULL || (ch0 < TOT);
  const int myhead = (HEADS == 1) ? 0 : (ch0 / C);
  float acc[V];
#pragma unroll
  for (int v = 0; v < V; ++v) acc[v] = 0.f;
  for (int i = r0; i < r1; ++i) {
    int e = eid[i];
    int s = (e < NEDGE) ? src_e[e] : (e - NEDGE);
    float a = alpha[(size_t)i * HEADS + myhead];
    if (active) {
      if constexpr (V == 4) {
        float4 hv = *(const float4*)(Hm + (size_t)s * TOT + ch0);
        acc[0] += a * hv.x; acc[1] += a * hv.y; acc[2] += a * hv.z; acc[3] += a * hv.w;
      } else if constexpr (V == 2) {
        float2 hv = *(const float2*)(Hm + (size_t)s * TOT + ch0);
        acc[0] += a * hv.x; acc[1] += a * hv.y;
      } else {
        acc[0] += a * Hm[(size_t)s * TOT + ch0];
      }
    }
  }
  if (active) {
#pragma unroll
    for (int v = 0; v < V; ++v) {
      int ch = ch0 + v;
      float val = acc[v] * rden[myhead] + bias[ch];
      if (ACT) val = (val > 0.f) ? val : 0.01f * val;
      outbuf[(size_t)n * TOT + ch] = val;
    }
  }
}

// ---------------- pooling + log_softmax ----------------

__global__ void k_pool(const float* __restrict__ out3, const int* __restrict__ batch,
                       float* __restrict__ pooled) {
  int idx = blockIdx.x * 256 + threadIdx.x;
  if (idx >= NNODES * C3) return;
  int n = idx / C3, c = idx - n * C3;
  atomicAdd(&pooled[(size_t)batch[n] * C3 + c], out3[idx]);
}

__global__ void k_lsm(const float* __restrict__ pooled, float* __restrict__ dout) {
  int g = blockIdx.x * 256 + threadIdx.x;
  if (g >= NGRAPH) return;
  float v[C3];
  float mx = -1e30f;
#pragma unroll
  for (int c = 0; c < C3; ++c) { v[c] = pooled[g * C3 + c]; mx = fmaxf(mx, v[c]); }
  float ssum = 0.f;
#pragma unroll
  for (int c = 0; c < C3; ++c) ssum += __expf(v[c] - mx);
  float lse = mx + __logf(ssum);
#pragma unroll
  for (int c = 0; c < C3; ++c) {
    dout[g * C3 + c] = v[c] - lse;               // log_softmax
    dout[NGRAPH * C3 + g * C3 + c] = v[c];       // pooled
  }
}

// ---------------- launcher ----------------

extern "C" void kernel_launch(void* const* d_in, const int* in_sizes, int n_in,
                              void* d_out, int out_size, void* d_ws, size_t ws_size,
                              hipStream_t stream) {
  (void)in_sizes; (void)n_in; (void)out_size; (void)ws_size;
  const float* x    = (const float*)d_in[0];
  const int*   eix  = (const int*)d_in[1];
  const int*   batch= (const int*)d_in[3];
  const float* W1   = (const float*)d_in[4];
  const float* as1  = (const float*)d_in[5];
  const float* ad1  = (const float*)d_in[6];
  const float* b1   = (const float*)d_in[7];
  const float* W2   = (const float*)d_in[8];
  const float* as2  = (const float*)d_in[9];
  const float* ad2  = (const float*)d_in[10];
  const float* b2   = (const float*)d_in[11];
  const float* W3   = (const float*)d_in[12];
  const float* as3  = (const float*)d_in[13];
  const float* ad3  = (const float*)d_in[14];
  const float* b3   = (const float*)d_in[15];
  const int* src_e = eix;
  const int* dst_e = eix + NEDGE;

  char* ws = (char*)d_ws;
  size_t off = 0;
  auto carve = [&](size_t bytes) -> char* {
    char* p = ws + off;
    off += (bytes + 511) & ~(size_t)511;
    return p;
  };
  int*   deg    = (int*)  carve((size_t)NNODES * 4);
  int*   rowptr = (int*)  carve((size_t)(NNODES + 1) * 4);
  int*   cursor = (int*)  carve((size_t)NNODES * 4);
  int*   eid    = (int*)  carve((size_t)ETOT * 4);
  float* alpha  = (float*)carve((size_t)ETOT * H1 * 4);
  float* als    = (float*)carve((size_t)NNODES * H1 * 4);
  float* ald    = (float*)carve((size_t)NNODES * H1 * 4);
  float* Hbuf   = (float*)carve((size_t)NNODES * O1 * 4);
  float* Xbuf   = (float*)carve((size_t)NNODES * O1 * 4);
  float* pooled = (float*)carve((size_t)NGRAPH * C3 * 4);

  hipMemsetAsync(deg, 0, (size_t)NNODES * 4, stream);
  hipMemsetAsync(pooled, 0, (size_t)NGRAPH * C3 * 4, stream);

  // CSR by destination (shared across all three layers)
  k_count  <<<(ETOT + 255) / 256, 256, 0, stream>>>(dst_e, deg);
  k_scan   <<<1, 1024, 0, stream>>>(deg, rowptr, cursor);
  k_scatter<<<(ETOT + 255) / 256, 256, 0, stream>>>(dst_e, cursor, eid);

  // conv1: 128 -> 4x64 (concat 256), leaky_relu(0.01)
  k_gemm<NFEAT, O1, 256, 16><<<NNODES / 16, 256, 0, stream>>>(x, W1, Hbuf);
  k_att<H1, 64><<<NNODES / 4, 256, 0, stream>>>(Hbuf, as1, ad1, als, ald);
  k_agg<H1, 64, true><<<NNODES / 4, 256, 0, stream>>>(rowptr, eid, src_e, Hbuf, als, ald, b1, alpha, Xbuf);

  // conv2: 256 -> 128, leaky_relu(0.01)
  k_gemm<O1, C2, 128, 16><<<NNODES / 16, 256, 0, stream>>>(Xbuf, W2, Hbuf);
  k_att<1, C2><<<NNODES / 4, 256, 0, stream>>>(Hbuf, as2, ad2, als, ald);
  k_agg<1, C2, true><<<NNODES / 4, 256, 0, stream>>>(rowptr, eid, src_e, Hbuf, als, ald, b2, alpha, Xbuf);

  // conv3: 128 -> 10, no activation
  k_gemm<C2, C3, 16, 16><<<NNODES / 16, 256, 0, stream>>>(Xbuf, W3, Hbuf);
  k_att<1, C3><<<NNODES / 4, 256, 0, stream>>>(Hbuf, as3, ad3, als, ald);
  k_agg<1, C3, false><<<NNODES / 4, 256, 0, stream>>>(rowptr, eid, src_e, Hbuf, als, ald, b3, alpha, Xbuf);

  // global_add_pool + log_softmax; output = [log_softmax | pooled]
  k_pool<<<(NNODES * C3 + 255) / 256, 256, 0, stream>>>(Xbuf, batch, pooled);
  k_lsm<<<(NGRAPH + 255) / 256, 256, 0, stream>>>(pooled, (float*)d_out);
}

// Round 2
// 428.064 us; speedup vs baseline: 1.8639x; 1.8639x over previous
//
#include <hip/hip_runtime.h>
#include <math.h>

#define NNODES 50000
#define MPAD   50048            // 782 * 64
#define NFEAT  128
#define NEDGE  800000
#define ETOT   (NEDGE + NNODES) // 850000 edges incl. self-loops
#define H1     4
#define O1     256              // heads1 * hid1
#define C2     128
#define C3     10
#define NGRAPH 512

typedef __attribute__((ext_vector_type(8))) short short8;
typedef __attribute__((ext_vector_type(4))) float f32x4;

__device__ __forceinline__ unsigned short f2b(float f) {
  unsigned int u = __float_as_uint(f);
  u += 0x7fffu + ((u >> 16) & 1u);
  return (unsigned short)(u >> 16);
}
__device__ __forceinline__ float b2f(unsigned short u) {
  return __uint_as_float(((unsigned int)u) << 16);
}

// ---------------- CSR build ----------------

__global__ void k_count(const int* __restrict__ dst_e, int* __restrict__ deg) {
  int e = blockIdx.x * 256 + threadIdx.x;
  if (e >= ETOT) return;
  int d = (e < NEDGE) ? dst_e[e] : (e - NEDGE);
  atomicAdd(&deg[d], 1);
}

__global__ __launch_bounds__(1024) void k_scan(const int* __restrict__ deg,
                                               int* __restrict__ rowptr,
                                               int* __restrict__ cursor) {
  __shared__ int wsum[16];
  __shared__ int carry_s;
  const int tid = threadIdx.x;
  const int lane = tid & 63, wid = tid >> 6;
  if (tid == 0) { carry_s = 0; rowptr[0] = 0; }
  __syncthreads();
  for (int base = 0; base < NNODES; base += 1024) {
    int idx = base + tid;
    int v = (idx < NNODES) ? deg[idx] : 0;
    int s = v;
#pragma unroll
    for (int off = 1; off < 64; off <<= 1) {
      int t = __shfl_up(s, off);
      if (lane >= off) s += t;
    }
    if (lane == 63) wsum[wid] = s;
    __syncthreads();
    int woff = carry_s;
#pragma unroll
    for (int k = 0; k < 16; ++k)
      if (k < wid) woff += wsum[k];
    int incl = woff + s;
    if (idx < NNODES) { rowptr[idx + 1] = incl; cursor[idx] = incl - v; }
    __syncthreads();
    if (tid == 1023) carry_s = incl;
    __syncthreads();
  }
}

__global__ void k_scatter(const int* __restrict__ src_e, const int* __restrict__ dst_e,
                          int* __restrict__ cursor, int* __restrict__ srcs) {
  int e = blockIdx.x * 256 + threadIdx.x;
  if (e >= ETOT) return;
  int d, s;
  if (e < NEDGE) { d = dst_e[e]; s = src_e[e]; }
  else           { d = e - NEDGE; s = e - NEDGE; }
  int pos = atomicAdd(&cursor[d], 1);
  srcs[pos] = s;
}

// ---------------- conversions / weight packing ----------------

__global__ void k_cvt(const float* __restrict__ X, unsigned short* __restrict__ Xb) {
  int idx = blockIdx.x * 256 + threadIdx.x;   // one per 4 elements of [MPAD][128]
  int base = idx * 4;
  if (base >= MPAD * NFEAT) return;
  int row = base >> 7;
  float4 v = make_float4(0.f, 0.f, 0.f, 0.f);
  if (row < NNODES) v = *(const float4*)(X + base);
  ushort4 o;
  o.x = f2b(v.x); o.y = f2b(v.y); o.z = f2b(v.z); o.w = f2b(v.w);
  *(ushort4*)(Xb + base) = o;
}

// Wp layout: [nt][ks][lane][8] so each lane's B fragment is one 16B load.
// element: k = ks*32 + (lane>>4)*8 + j ; n = nt*16 + (lane&15)
template<int K, int N>
__global__ void k_packW(const float* __restrict__ W, unsigned short* __restrict__ Wp,
                        int nsrc) {
  constexpr int KS = K / 32;
  int idx = blockIdx.x * 256 + threadIdx.x;
  if (idx >= K * N) return;
  int j = idx & 7;
  int lane = (idx >> 3) & 63;
  int t = idx >> 9;            // nt*KS + ks
  int ks = t % KS;
  int nt = t / KS;
  int k = ks * 32 + (lane >> 4) * 8 + j;
  int n = nt * 16 + (lane & 15);
  float v = (n < nsrc) ? W[(size_t)k * nsrc + n] : 0.f;
  Wp[idx] = f2b(v);
}

// ---------------- MFMA GEMM: Hout[MPAD][N] (bf16) = Xb[MPAD][K] @ W[K][N] ----------------

template<int K, int N>
__global__ __launch_bounds__(256) void k_mm(const unsigned short* __restrict__ Xb,
                                            const unsigned short* __restrict__ Wp,
                                            unsigned short* __restrict__ Hout) {
  constexpr int KS = K / 32, NT = N / 16;
  const int w = threadIdx.x >> 6, lane = threadIdx.x & 63;
  const int arow = blockIdx.x * 64 + w * 16 + (lane & 15);
  const int k0 = (lane >> 4) * 8;
  f32x4 acc[NT] = {};
  for (int ks = 0; ks < KS; ++ks) {
    short8 a = *(const short8*)(Xb + (size_t)arow * K + ks * 32 + k0);
    const short8* bp = (const short8*)Wp + (size_t)ks * 64 + lane;
#pragma unroll
    for (int nt = 0; nt < NT; ++nt) {
      short8 b = bp[(size_t)nt * KS * 64];
      acc[nt] = __builtin_amdgcn_mfma_f32_16x16x32_bf16(a, b, acc[nt], 0, 0, 0);
    }
  }
  const int col = lane & 15;
  const int rbase = blockIdx.x * 64 + w * 16 + (lane >> 4) * 4;
#pragma unroll
  for (int nt = 0; nt < NT; ++nt)
#pragma unroll
    for (int j = 0; j < 4; ++j)
      Hout[(size_t)(rbase + j) * N + nt * 16 + col] = f2b(acc[nt][j]);
}

// ---------------- attention logits per node ----------------

template<int HEADS, int C, int SR>
__global__ __launch_bounds__(256) void k_att(const unsigned short* __restrict__ Hm,
                                             const float* __restrict__ a_src,
                                             const float* __restrict__ a_dst,
                                             float* __restrict__ als,
                                             float* __restrict__ ald) {
  constexpr int TOT = HEADS * C;
  constexpr int V = (TOT + 63) / 64;
  const int n = blockIdx.x * 4 + (threadIdx.x >> 6);
  const int lane = threadIdx.x & 63;
  const int ch0 = lane * V;
  float s = 0.f, d = 0.f;
  if ((TOT % 64 == 0) || ch0 < TOT) {
    if constexpr (V == 4) {
      ushort4 hv = *(const ushort4*)(Hm + (size_t)n * SR + ch0);
      float h0 = b2f(hv.x), h1 = b2f(hv.y), h2 = b2f(hv.z), h3 = b2f(hv.w);
      s = h0 * a_src[ch0] + h1 * a_src[ch0 + 1] + h2 * a_src[ch0 + 2] + h3 * a_src[ch0 + 3];
      d = h0 * a_dst[ch0] + h1 * a_dst[ch0 + 1] + h2 * a_dst[ch0 + 2] + h3 * a_dst[ch0 + 3];
    } else if constexpr (V == 2) {
      ushort2 hv = *(const ushort2*)(Hm + (size_t)n * SR + ch0);
      float h0 = b2f(hv.x), h1 = b2f(hv.y);
      s = h0 * a_src[ch0] + h1 * a_src[ch0 + 1];
      d = h0 * a_dst[ch0] + h1 * a_dst[ch0 + 1];
    } else {
      float h0 = b2f(Hm[(size_t)n * SR + ch0]);
      s = h0 * a_src[ch0];
      d = h0 * a_dst[ch0];
    }
  }
  constexpr int RW = (HEADS == 1) ? 64 : 16;
#pragma unroll
  for (int m = 1; m < RW; m <<= 1) { s += __shfl_xor(s, m); d += __shfl_xor(d, m); }
  if ((lane & (RW - 1)) == 0) {
    int h = lane / RW;
    als[(size_t)n * HEADS + h] = s;
    ald[(size_t)n * HEADS + h] = d;
  }
}

// ---------------- single-pass softmax + aggregation, one wave per dst node ----------------
// out[n] = (sum_e exp(lrelu(als[s]+ald[n])) * h[s]) / (sum_e exp(...))

template<int HEADS, int C, int SR, int OSR, bool ACT, bool OUTF32>
__global__ __launch_bounds__(256) void k_agg(const int* __restrict__ rowptr,
                                             const int* __restrict__ srcs,
                                             const unsigned short* __restrict__ Hm,
                                             const float* __restrict__ als,
                                             const float* __restrict__ ald,
                                             const float* __restrict__ bias,
                                             unsigned short* __restrict__ outb,
                                             float* __restrict__ outf) {
  constexpr int TOT = HEADS * C;
  constexpr int V = (TOT + 63) / 64;
  const int n = blockIdx.x * 4 + (threadIdx.x >> 6);
  const int lane = threadIdx.x & 63;
  const int r0 = rowptr[n], r1 = rowptr[n + 1];
  const int ch0 = lane * V;
  const bool active = (TOT % 64 == 0) || (ch0 < TOT);
  const int myhead = (HEADS == 1) ? 0 : (ch0 / C);
  const float aldm = ald[(size_t)n * HEADS + myhead];
  float den = 0.f;
  float acc[V];
#pragma unroll
  for (int v = 0; v < V; ++v) acc[v] = 0.f;

  auto edge = [&](int i) {
    int s = srcs[i];
    float ev = als[(size_t)s * HEADS + myhead] + aldm;
    ev = (ev > 0.f) ? ev : 0.2f * ev;
    float ex = __expf(ev);
    den += ex;
    if (active) {
      if constexpr (V == 4) {
        ushort4 hv = *(const ushort4*)(Hm + (size_t)s * SR + ch0);
        acc[0] += ex * b2f(hv.x); acc[1] += ex * b2f(hv.y);
        acc[2] += ex * b2f(hv.z); acc[3] += ex * b2f(hv.w);
      } else if constexpr (V == 2) {
        ushort2 hv = *(const ushort2*)(Hm + (size_t)s * SR + ch0);
        acc[0] += ex * b2f(hv.x); acc[1] += ex * b2f(hv.y);
      } else {
        acc[0] += ex * b2f(Hm[(size_t)s * SR + ch0]);
      }
    }
  };
  int i = r0;
  for (; i + 4 <= r1; i += 4) { edge(i); edge(i + 1); edge(i + 2); edge(i + 3); }
  for (; i < r1; ++i) edge(i);

  const float rden = 1.f / (den + 1e-16f);
  if (active) {
    if constexpr (!OUTF32) {
      if constexpr (V == 4) {
        ushort4 o;
        float v0 = acc[0] * rden + bias[ch0 + 0];
        float v1 = acc[1] * rden + bias[ch0 + 1];
        float v2 = acc[2] * rden + bias[ch0 + 2];
        float v3 = acc[3] * rden + bias[ch0 + 3];
        if (ACT) {
          v0 = (v0 > 0.f) ? v0 : 0.01f * v0; v1 = (v1 > 0.f) ? v1 : 0.01f * v1;
          v2 = (v2 > 0.f) ? v2 : 0.01f * v2; v3 = (v3 > 0.f) ? v3 : 0.01f * v3;
        }
        o.x = f2b(v0); o.y = f2b(v1); o.z = f2b(v2); o.w = f2b(v3);
        *(ushort4*)(outb + (size_t)n * OSR + ch0) = o;
      } else if constexpr (V == 2) {
        ushort2 o;
        float v0 = acc[0] * rden + bias[ch0 + 0];
        float v1 = acc[1] * rden + bias[ch0 + 1];
        if (ACT) { v0 = (v0 > 0.f) ? v0 : 0.01f * v0; v1 = (v1 > 0.f) ? v1 : 0.01f * v1; }
        o.x = f2b(v0); o.y = f2b(v1);
        *(ushort2*)(outb + (size_t)n * OSR + ch0) = o;
      } else {
        float v0 = acc[0] * rden + bias[ch0];
        if (ACT) v0 = (v0 > 0.f) ? v0 : 0.01f * v0;
        outb[(size_t)n * OSR + ch0] = f2b(v0);
      }
    } else {
#pragma unroll
      for (int v = 0; v < V; ++v) {
        float val = acc[v] * rden + bias[ch0 + v];
        if (ACT) val = (val > 0.f) ? val : 0.01f * val;
        outf[(size_t)n * OSR + ch0 + v] = val;
      }
    }
  }
}

// ---------------- pooling + log_softmax ----------------

__global__ void k_pool(const float* __restrict__ out3, const int* __restrict__ batch,
                       float* __restrict__ pooled) {
  int idx = blockIdx.x * 256 + threadIdx.x;
  if (idx >= NNODES * C3) return;
  int n = idx / C3, c = idx - n * C3;
  atomicAdd(&pooled[(size_t)batch[n] * C3 + c], out3[idx]);
}

__global__ void k_lsm(const float* __restrict__ pooled, float* __restrict__ dout) {
  int g = blockIdx.x * 256 + threadIdx.x;
  if (g >= NGRAPH) return;
  float v[C3];
  float mx = -1e30f;
#pragma unroll
  for (int c = 0; c < C3; ++c) { v[c] = pooled[g * C3 + c]; mx = fmaxf(mx, v[c]); }
  float ssum = 0.f;
#pragma unroll
  for (int c = 0; c < C3; ++c) ssum += __expf(v[c] - mx);
  float lse = mx + __logf(ssum);
#pragma unroll
  for (int c = 0; c < C3; ++c) {
    dout[g * C3 + c] = v[c] - lse;               // log_softmax
    dout[NGRAPH * C3 + g * C3 + c] = v[c];       // pooled
  }
}

// ---------------- launcher ----------------

extern "C" void kernel_launch(void* const* d_in, const int* in_sizes, int n_in,
                              void* d_out, int out_size, void* d_ws, size_t ws_size,
                              hipStream_t stream) {
  (void)in_sizes; (void)n_in; (void)out_size; (void)ws_size;
  const float* x     = (const float*)d_in[0];
  const int*   eix   = (const int*)d_in[1];
  const int*   batch = (const int*)d_in[3];
  const float* W1 = (const float*)d_in[4];
  const float* as1 = (const float*)d_in[5];
  const float* ad1 = (const float*)d_in[6];
  const float* b1 = (const float*)d_in[7];
  const float* W2 = (const float*)d_in[8];
  const float* as2 = (const float*)d_in[9];
  const float* ad2 = (const float*)d_in[10];
  const float* b2 = (const float*)d_in[11];
  const float* W3 = (const float*)d_in[12];
  const float* as3 = (const float*)d_in[13];
  const float* ad3 = (const float*)d_in[14];
  const float* b3 = (const float*)d_in[15];
  const int* src_e = eix;
  const int* dst_e = eix + NEDGE;

  char* ws = (char*)d_ws;
  size_t off = 0;
  auto carve = [&](size_t bytes) -> char* {
    char* p = ws + off;
    off += (bytes + 511) & ~(size_t)511;
    return p;
  };
  int* deg    = (int*)carve((size_t)NNODES * 4);
  int* rowptr = (int*)carve((size_t)(NNODES + 1) * 4);
  int* cursor = (int*)carve((size_t)NNODES * 4);
  int* srcs   = (int*)carve((size_t)ETOT * 4);
  float* als  = (float*)carve((size_t)NNODES * H1 * 4);
  float* ald  = (float*)carve((size_t)NNODES * H1 * 4);
  unsigned short* Xb  = (unsigned short*)carve((size_t)MPAD * NFEAT * 2);  // x bf16
  unsigned short* Hb  = (unsigned short*)carve((size_t)MPAD * O1 * 2);     // gemm out (max 256)
  unsigned short* Xc  = (unsigned short*)carve((size_t)MPAD * O1 * 2);     // agg out (max 256)
  unsigned short* H3b = (unsigned short*)carve((size_t)MPAD * 16 * 2);
  float* out3   = (float*)carve((size_t)NNODES * C3 * 4);
  float* pooled = (float*)carve((size_t)NGRAPH * C3 * 4);
  unsigned short* W1p = (unsigned short*)carve((size_t)NFEAT * O1 * 2);
  unsigned short* W2p = (unsigned short*)carve((size_t)O1 * C2 * 2);
  unsigned short* W3p = (unsigned short*)carve((size_t)C2 * 16 * 2);

  hipMemsetAsync(deg, 0, (size_t)NNODES * 4, stream);
  hipMemsetAsync(pooled, 0, (size_t)NGRAPH * C3 * 4, stream);

  // CSR by destination (shared across layers), storing src ids directly
  k_count  <<<(ETOT + 255) / 256, 256, 0, stream>>>(dst_e, deg);
  k_scan   <<<1, 1024, 0, stream>>>(deg, rowptr, cursor);
  k_scatter<<<(ETOT + 255) / 256, 256, 0, stream>>>(src_e, dst_e, cursor, srcs);

  // input conversion + weight packing
  k_cvt<<<(MPAD * NFEAT / 4 + 255) / 256, 256, 0, stream>>>(x, Xb);
  k_packW<NFEAT, O1><<<(NFEAT * O1 + 255) / 256, 256, 0, stream>>>(W1, W1p, O1);
  k_packW<O1, C2><<<(O1 * C2 + 255) / 256, 256, 0, stream>>>(W2, W2p, C2);
  k_packW<C2, 16><<<(C2 * 16 + 255) / 256, 256, 0, stream>>>(W3, W3p, C3);

  const int GB = MPAD / 64;       // 782 gemm blocks
  const int NB = NNODES / 4;      // 12500 node blocks

  // conv1: 128 -> 4x64 (concat 256), leaky_relu(0.01)
  k_mm<NFEAT, O1><<<GB, 256, 0, stream>>>(Xb, W1p, Hb);
  k_att<H1, 64, O1><<<NB, 256, 0, stream>>>(Hb, as1, ad1, als, ald);
  k_agg<H1, 64, O1, O1, true, false><<<NB, 256, 0, stream>>>(rowptr, srcs, Hb, als, ald, b1, Xc, nullptr);

  // conv2: 256 -> 128, leaky_relu(0.01)
  k_mm<O1, C2><<<GB, 256, 0, stream>>>(Xc, W2p, Hb);
  k_att<1, C2, C2><<<NB, 256, 0, stream>>>(Hb, as2, ad2, als, ald);
  k_agg<1, C2, C2, C2, true, false><<<NB, 256, 0, stream>>>(rowptr, srcs, Hb, als, ald, b2, Xc, nullptr);

  // conv3: 128 -> 10 (padded to 16), no activation, f32 out
  k_mm<C2, 16><<<GB, 256, 0, stream>>>(Xc, W3p, H3b);
  k_att<1, C3, 16><<<NB, 256, 0, stream>>>(H3b, as3, ad3, als, ald);
  k_agg<1, C3, 16, C3, false, true><<<NB, 256, 0, stream>>>(rowptr, srcs, H3b, als, ald, b3, nullptr, out3);

  // global_add_pool + log_softmax; output = [log_softmax | pooled]
  k_pool<<<(NNODES * C3 + 255) / 256, 256, 0, stream>>>(out3, batch, pooled);
  k_lsm<<<(NGRAPH + 255) / 256, 256, 0, stream>>>(pooled, (float*)d_out);
}

// Round 3
// 399.036 us; speedup vs baseline: 1.9995x; 1.0727x over previous
//
#include <hip/hip_runtime.h>
#include <math.h>

#define NNODES 50000
#define MPAD   50048            // 782 * 64
#define NFEAT  128
#define NEDGE  800000
#define ETOT   (NEDGE + NNODES) // 850000 edges incl. self-loops
#define H1     4
#define O1     256              // heads1 * hid1
#define C2     128
#define C3     10
#define NGRAPH 512

typedef __attribute__((ext_vector_type(8))) short short8;
typedef __attribute__((ext_vector_type(4))) float f32x4;

__device__ __forceinline__ unsigned short f2b(float f) {
  unsigned int u = __float_as_uint(f);
  u += 0x7fffu + ((u >> 16) & 1u);
  return (unsigned short)(u >> 16);
}
__device__ __forceinline__ float b2f(unsigned short u) {
  return __uint_as_float(((unsigned int)u) << 16);
}
__device__ __forceinline__ float readlane_f(float v, int l) {
  return __uint_as_float((unsigned)__builtin_amdgcn_readlane(__float_as_uint(v), l));
}

// ---------------- CSR build ----------------

__global__ void k_count(const int* __restrict__ dst_e, int* __restrict__ deg) {
  int e = blockIdx.x * 256 + threadIdx.x;
  if (e >= ETOT) return;
  int d = (e < NEDGE) ? dst_e[e] : (e - NEDGE);
  atomicAdd(&deg[d], 1);
}

__global__ __launch_bounds__(1024) void k_scan(const int* __restrict__ deg,
                                               int* __restrict__ rowptr,
                                               int* __restrict__ cursor) {
  __shared__ int wsum[16];
  __shared__ int carry_s;
  const int tid = threadIdx.x;
  const int lane = tid & 63, wid = tid >> 6;
  if (tid == 0) { carry_s = 0; rowptr[0] = 0; }
  __syncthreads();
  for (int base = 0; base < NNODES; base += 1024) {
    int idx = base + tid;
    int v = (idx < NNODES) ? deg[idx] : 0;
    int s = v;
#pragma unroll
    for (int off = 1; off < 64; off <<= 1) {
      int t = __shfl_up(s, off);
      if (lane >= off) s += t;
    }
    if (lane == 63) wsum[wid] = s;
    __syncthreads();
    int woff = carry_s;
#pragma unroll
    for (int k = 0; k < 16; ++k)
      if (k < wid) woff += wsum[k];
    int incl = woff + s;
    if (idx < NNODES) { rowptr[idx + 1] = incl; cursor[idx] = incl - v; }
    __syncthreads();
    if (tid == 1023) carry_s = incl;
    __syncthreads();
  }
}

__global__ void k_scatter(const int* __restrict__ src_e, const int* __restrict__ dst_e,
                          int* __restrict__ cursor, int* __restrict__ srcs) {
  int e = blockIdx.x * 256 + threadIdx.x;
  if (e >= ETOT) return;
  int d, s;
  if (e < NEDGE) { d = dst_e[e]; s = src_e[e]; }
  else           { d = e - NEDGE; s = e - NEDGE; }
  int pos = atomicAdd(&cursor[d], 1);
  srcs[pos] = s;
}

// ---------------- conversions / weight packing ----------------

__global__ void k_cvt(const float* __restrict__ X, unsigned short* __restrict__ Xb) {
  int idx = blockIdx.x * 256 + threadIdx.x;   // one per 4 elements of [MPAD][128]
  int base = idx * 4;
  if (base >= MPAD * NFEAT) return;
  int row = base >> 7;
  float4 v = make_float4(0.f, 0.f, 0.f, 0.f);
  if (row < NNODES) v = *(const float4*)(X + base);
  ushort4 o;
  o.x = f2b(v.x); o.y = f2b(v.y); o.z = f2b(v.z); o.w = f2b(v.w);
  *(ushort4*)(Xb + base) = o;
}

// Wp layout: [nt][ks][lane][8] so each lane's B fragment is one 16B load.
// element: k = ks*32 + (lane>>4)*8 + j ; n = nt*16 + (lane&15)
template<int K, int N>
__global__ void k_packW(const float* __restrict__ W, unsigned short* __restrict__ Wp,
                        int nsrc) {
  constexpr int KS = K / 32;
  int idx = blockIdx.x * 256 + threadIdx.x;
  if (idx >= K * N) return;
  int j = idx & 7;
  int lane = (idx >> 3) & 63;
  int t = idx >> 9;            // nt*KS + ks
  int ks = t % KS;
  int nt = t / KS;
  int k = ks * 32 + (lane >> 4) * 8 + j;
  int n = nt * 16 + (lane & 15);
  float v = (n < nsrc) ? W[(size_t)k * nsrc + n] : 0.f;
  Wp[idx] = f2b(v);
}

// ---------------- MFMA GEMM + fused attention-logit epilogue ----------------
// Hout[MPAD][N] (bf16) = Xb[MPAD][K] @ W[K][N]; als/ald[row][HEADS] = H·a_src / H·a_dst

template<int K, int N, int HEADS, int CREAL>
__global__ __launch_bounds__(256) void k_mm(const unsigned short* __restrict__ Xb,
                                            const unsigned short* __restrict__ Wp,
                                            unsigned short* __restrict__ Hout,
                                            const float* __restrict__ a_src,
                                            const float* __restrict__ a_dst,
                                            float* __restrict__ als,
                                            float* __restrict__ ald) {
  constexpr int KS = K / 32, NT = N / 16;
  constexpr int NTH = (NT + HEADS - 1) / HEADS;   // nts per head
  const int w = threadIdx.x >> 6, lane = threadIdx.x & 63;
  const int arow = blockIdx.x * 64 + w * 16 + (lane & 15);
  const int k0 = (lane >> 4) * 8;
  f32x4 acc[NT] = {};
  for (int ks = 0; ks < KS; ++ks) {
    short8 a = *(const short8*)(Xb + (size_t)arow * K + ks * 32 + k0);
    const short8* bp = (const short8*)Wp + (size_t)ks * 64 + lane;
#pragma unroll
    for (int nt = 0; nt < NT; ++nt) {
      short8 b = bp[(size_t)nt * KS * 64];
      acc[nt] = __builtin_amdgcn_mfma_f32_16x16x32_bf16(a, b, acc[nt], 0, 0, 0);
    }
  }
  const int col = lane & 15;
  const int rbase = blockIdx.x * 64 + w * 16 + (lane >> 4) * 4;
#pragma unroll
  for (int nt = 0; nt < NT; ++nt)
#pragma unroll
    for (int j = 0; j < 4; ++j)
      Hout[(size_t)(rbase + j) * N + nt * 16 + col] = f2b(acc[nt][j]);

  // fused attention logits: per-row dot with a_src/a_dst over channels (N dim)
  float av[NT], dv[NT];
#pragma unroll
  for (int nt = 0; nt < NT; ++nt) {
    int ch = nt * 16 + col;
    av[nt] = (ch < CREAL) ? a_src[ch] : 0.f;
    dv[nt] = (ch < CREAL) ? a_dst[ch] : 0.f;
  }
  float sa[HEADS][4], da[HEADS][4];
#pragma unroll
  for (int h = 0; h < HEADS; ++h)
#pragma unroll
    for (int j = 0; j < 4; ++j) { sa[h][j] = 0.f; da[h][j] = 0.f; }
#pragma unroll
  for (int nt = 0; nt < NT; ++nt) {
    int h = nt / NTH;
#pragma unroll
    for (int j = 0; j < 4; ++j) {
      sa[h][j] += acc[nt][j] * av[nt];
      da[h][j] += acc[nt][j] * dv[nt];
    }
  }
#pragma unroll
  for (int mask = 1; mask < 16; mask <<= 1)
#pragma unroll
    for (int h = 0; h < HEADS; ++h)
#pragma unroll
      for (int j = 0; j < 4; ++j) {
        sa[h][j] += __shfl_xor(sa[h][j], mask);
        da[h][j] += __shfl_xor(da[h][j], mask);
      }
  if (col == 0) {
#pragma unroll
    for (int j = 0; j < 4; ++j)
#pragma unroll
      for (int h = 0; h < HEADS; ++h) {
        als[(size_t)(rbase + j) * HEADS + h] = sa[h][j];
        ald[(size_t)(rbase + j) * HEADS + h] = da[h][j];
      }
  }
}

// ---------------- single-pass softmax + aggregation, one wave per dst node ----
// Prefetch scheme: per chunk, each lane precomputes exp(lrelu(als[s]+ald[n])) for
// one edge; inner loop broadcasts (readlane/bpermute) and does ONLY the feature
// gather + FMA. OMODE: 0 = bf16 store, 2 = fused pool atomicAdd (layer 3).

template<int HEADS, int C, int SR, bool ACT, int OMODE>
__global__ __launch_bounds__(256) void k_agg(const int* __restrict__ rowptr,
                                             const int* __restrict__ srcs,
                                             const unsigned short* __restrict__ Hm,
                                             const float* __restrict__ als,
                                             const float* __restrict__ ald,
                                             const float* __restrict__ bias,
                                             unsigned short* __restrict__ outb,
                                             float* __restrict__ pooled,
                                             const int* __restrict__ batch) {
  constexpr int TOT = HEADS * C;
  constexpr int V = (TOT + 63) / 64;
  const int n = blockIdx.x * 4 + (threadIdx.x >> 6);
  const int lane = threadIdx.x & 63;
  const int r0 = rowptr[n], r1 = rowptr[n + 1];
  const int ch0 = lane * V;
  const bool active = (TOT % 64 == 0) || (ch0 < TOT);
  const int myhead = (HEADS == 1) ? 0 : (ch0 / C);
  const float aldm = ald[(size_t)n * HEADS + myhead];
  float acc[V];
#pragma unroll
  for (int v = 0; v < V; ++v) acc[v] = 0.f;
  float den = 0.f;

  if constexpr (HEADS == 4) {
    // chunk of 16 edges; lane role: e_lane = lane&15 (edge), head = lane>>4
    const int e_lane = lane & 15;
    const int baddr = (lane & 48) << 2;         // bpermute byte base
    for (int i0 = r0; i0 < r1; i0 += 16) {
      const int take = min(16, r1 - i0);
      int sidx = srcs[min(i0 + e_lane, r1 - 1)];
      float al = als[(size_t)sidx * 4 + (lane >> 4)];
      float ev = al + aldm;
      ev = (ev > 0.f) ? ev : 0.2f * ev;
      float exv = (e_lane < take) ? __expf(ev) : 0.f;
      den += exv;
#pragma unroll 4
      for (int m = 0; m < take; ++m) {
        int s = __builtin_amdgcn_readlane(sidx, m);
        float ex = __uint_as_float(
            (unsigned)__builtin_amdgcn_ds_bpermute(baddr + m * 4, (int)__float_as_uint(exv)));
        ushort4 hv = *(const ushort4*)(Hm + (size_t)s * SR + ch0);
        acc[0] += ex * b2f(hv.x); acc[1] += ex * b2f(hv.y);
        acc[2] += ex * b2f(hv.z); acc[3] += ex * b2f(hv.w);
      }
    }
    // denominator: sum over the 16 e_lanes within each head group
#pragma unroll
    for (int mask = 1; mask < 16; mask <<= 1) den += __shfl_xor(den, mask);
  } else {
    // chunk of 64 edges
    for (int i0 = r0; i0 < r1; i0 += 64) {
      const int take = min(64, r1 - i0);
      int sidx = srcs[min(i0 + lane, r1 - 1)];
      float al = als[sidx];
      float ev = al + aldm;
      ev = (ev > 0.f) ? ev : 0.2f * ev;
      float exv = (lane < take) ? __expf(ev) : 0.f;
      den += exv;
#pragma unroll 8
      for (int m = 0; m < take; ++m) {
        int s = __builtin_amdgcn_readlane(sidx, m);
        float ex = readlane_f(exv, m);
        if (active) {
          if constexpr (V == 2) {
            ushort2 hv = *(const ushort2*)(Hm + (size_t)s * SR + ch0);
            acc[0] += ex * b2f(hv.x); acc[1] += ex * b2f(hv.y);
          } else {
            acc[0] += ex * b2f(Hm[(size_t)s * SR + ch0]);
          }
        }
      }
    }
#pragma unroll
    for (int mask = 1; mask < 64; mask <<= 1) den += __shfl_xor(den, mask);
  }

  const float rden = 1.f / (den + 1e-16f);
  if constexpr (OMODE == 0) {
    if (active) {
      if constexpr (V == 4) {
        float v0 = acc[0] * rden + bias[ch0 + 0];
        float v1 = acc[1] * rden + bias[ch0 + 1];
        float v2 = acc[2] * rden + bias[ch0 + 2];
        float v3 = acc[3] * rden + bias[ch0 + 3];
        if (ACT) {
          v0 = (v0 > 0.f) ? v0 : 0.01f * v0; v1 = (v1 > 0.f) ? v1 : 0.01f * v1;
          v2 = (v2 > 0.f) ? v2 : 0.01f * v2; v3 = (v3 > 0.f) ? v3 : 0.01f * v3;
        }
        ushort4 o; o.x = f2b(v0); o.y = f2b(v1); o.z = f2b(v2); o.w = f2b(v3);
        *(ushort4*)(outb + (size_t)n * TOT + ch0) = o;
      } else if constexpr (V == 2) {
        float v0 = acc[0] * rden + bias[ch0 + 0];
        float v1 = acc[1] * rden + bias[ch0 + 1];
        if (ACT) { v0 = (v0 > 0.f) ? v0 : 0.01f * v0; v1 = (v1 > 0.f) ? v1 : 0.01f * v1; }
        ushort2 o; o.x = f2b(v0); o.y = f2b(v1);
        *(ushort2*)(outb + (size_t)n * TOT + ch0) = o;
      } else {
        float v0 = acc[0] * rden + bias[ch0];
        if (ACT) v0 = (v0 > 0.f) ? v0 : 0.01f * v0;
        outb[(size_t)n * TOT + ch0] = f2b(v0);
      }
    }
  } else {
    // fused global_add_pool (layer 3): V==1, C==10
    if (lane < TOT) {
      float val = acc[0] * rden + bias[lane];
      atomicAdd(&pooled[(size_t)batch[n] * C3 + lane], val);
    }
  }
}

// ---------------- log_softmax ----------------

__global__ void k_lsm(const float* __restrict__ pooled, float* __restrict__ dout) {
  int g = blockIdx.x * 256 + threadIdx.x;
  if (g >= NGRAPH) return;
  float v[C3];
  float mx = -1e30f;
#pragma unroll
  for (int c = 0; c < C3; ++c) { v[c] = pooled[g * C3 + c]; mx = fmaxf(mx, v[c]); }
  float ssum = 0.f;
#pragma unroll
  for (int c = 0; c < C3; ++c) ssum += __expf(v[c] - mx);
  float lse = mx + __logf(ssum);
#pragma unroll
  for (int c = 0; c < C3; ++c) {
    dout[g * C3 + c] = v[c] - lse;               // log_softmax
    dout[NGRAPH * C3 + g * C3 + c] = v[c];       // pooled
  }
}

// ---------------- launcher ----------------

extern "C" void kernel_launch(void* const* d_in, const int* in_sizes, int n_in,
                              void* d_out, int out_size, void* d_ws, size_t ws_size,
                              hipStream_t stream) {
  (void)in_sizes; (void)n_in; (void)out_size; (void)ws_size;
  const float* x     = (const float*)d_in[0];
  const int*   eix   = (const int*)d_in[1];
  const int*   batch = (const int*)d_in[3];
  const float* W1 = (const float*)d_in[4];
  const float* as1 = (const float*)d_in[5];
  const float* ad1 = (const float*)d_in[6];
  const float* b1 = (const float*)d_in[7];
  const float* W2 = (const float*)d_in[8];
  const float* as2 = (const float*)d_in[9];
  const float* ad2 = (const float*)d_in[10];
  const float* b2 = (const float*)d_in[11];
  const float* W3 = (const float*)d_in[12];
  const float* as3 = (const float*)d_in[13];
  const float* ad3 = (const float*)d_in[14];
  const float* b3 = (const float*)d_in[15];
  const int* src_e = eix;
  const int* dst_e = eix + NEDGE;

  char* ws = (char*)d_ws;
  size_t off = 0;
  auto carve = [&](size_t bytes) -> char* {
    char* p = ws + off;
    off += (bytes + 511) & ~(size_t)511;
    return p;
  };
  int* deg    = (int*)carve((size_t)NNODES * 4);
  int* rowptr = (int*)carve((size_t)(NNODES + 1) * 4);
  int* cursor = (int*)carve((size_t)NNODES * 4);
  int* srcs   = (int*)carve((size_t)ETOT * 4);
  float* als  = (float*)carve((size_t)MPAD * H1 * 4);
  float* ald  = (float*)carve((size_t)MPAD * H1 * 4);
  unsigned short* Xb  = (unsigned short*)carve((size_t)MPAD * NFEAT * 2);
  unsigned short* Hb  = (unsigned short*)carve((size_t)MPAD * O1 * 2);
  unsigned short* Xc  = (unsigned short*)carve((size_t)MPAD * O1 * 2);
  unsigned short* H3b = (unsigned short*)carve((size_t)MPAD * 16 * 2);
  float* pooled = (float*)carve((size_t)NGRAPH * C3 * 4);
  unsigned short* W1p = (unsigned short*)carve((size_t)NFEAT * O1 * 2);
  unsigned short* W2p = (unsigned short*)carve((size_t)O1 * C2 * 2);
  unsigned short* W3p = (unsigned short*)carve((size_t)C2 * 16 * 2);

  hipMemsetAsync(deg, 0, (size_t)NNODES * 4, stream);
  hipMemsetAsync(pooled, 0, (size_t)NGRAPH * C3 * 4, stream);

  // CSR by destination (shared across layers), storing src ids directly
  k_count  <<<(ETOT + 255) / 256, 256, 0, stream>>>(dst_e, deg);
  k_scan   <<<1, 1024, 0, stream>>>(deg, rowptr, cursor);
  k_scatter<<<(ETOT + 255) / 256, 256, 0, stream>>>(src_e, dst_e, cursor, srcs);

  // input conversion + weight packing
  k_cvt<<<(MPAD * NFEAT / 4 + 255) / 256, 256, 0, stream>>>(x, Xb);
  k_packW<NFEAT, O1><<<(NFEAT * O1 + 255) / 256, 256, 0, stream>>>(W1, W1p, O1);
  k_packW<O1, C2><<<(O1 * C2 + 255) / 256, 256, 0, stream>>>(W2, W2p, C2);
  k_packW<C2, 16><<<(C2 * 16 + 255) / 256, 256, 0, stream>>>(W3, W3p, C3);

  const int GB = MPAD / 64;       // 782 gemm blocks
  const int NB = NNODES / 4;      // 12500 node blocks

  // conv1: 128 -> 4x64 (concat 256), leaky_relu(0.01)
  k_mm<NFEAT, O1, H1, O1><<<GB, 256, 0, stream>>>(Xb, W1p, Hb, as1, ad1, als, ald);
  k_agg<H1, 64, O1, true, 0><<<NB, 256, 0, stream>>>(rowptr, srcs, Hb, als, ald, b1, Xc, nullptr, nullptr);

  // conv2: 256 -> 128, leaky_relu(0.01)
  k_mm<O1, C2, 1, C2><<<GB, 256, 0, stream>>>(Xc, W2p, Hb, as2, ad2, als, ald);
  k_agg<1, C2, C2, true, 0><<<NB, 256, 0, stream>>>(rowptr, srcs, Hb, als, ald, b2, Xc, nullptr, nullptr);

  // conv3: 128 -> 10 (padded to 16), no activation, fused pool
  k_mm<C2, 16, 1, C3><<<GB, 256, 0, stream>>>(Xc, W3p, H3b, as3, ad3, als, ald);
  k_agg<1, C3, 16, false, 2><<<NB, 256, 0, stream>>>(rowptr, srcs, H3b, als, ald, b3, nullptr, pooled, batch);

  // log_softmax; output = [log_softmax | pooled]
  k_lsm<<<(NGRAPH + 255) / 256, 256, 0, stream>>>(pooled, (float*)d_out);
}